// Round 1
// baseline (1110.846 us; speedup 1.0000x reference)
//
#include <hip/hip_runtime.h>

#define N_NODES 100000
#define E_EDGES 1600000
#define EP (E_EDGES + N_NODES)
#define NG 1024
#define NEG 0.2f
#define EPS_BN 1e-5f

// ---------------- CSR build (by destination) ----------------
__global__ void k_count(const int* __restrict__ ei, int* __restrict__ cnt) {
    int e = blockIdx.x * 256 + threadIdx.x;
    if (e >= EP) return;
    int d = (e < E_EDGES) ? ei[E_EDGES + e] : (e - E_EDGES);
    atomicAdd(&cnt[d], 1);
}

__global__ void k_alloc(const int* __restrict__ cnt, int* __restrict__ startA,
                        int* __restrict__ curA, int* __restrict__ cursor) {
    int n = blockIdx.x * 256 + threadIdx.x;
    if (n >= N_NODES) return;
    int c = cnt[n];
    int s = atomicAdd(cursor, c);
    startA[n] = s;
    curA[n] = s;
}

__global__ void k_scatter(const int* __restrict__ ei, int* __restrict__ curA,
                          int* __restrict__ colA) {
    int e = blockIdx.x * 256 + threadIdx.x;
    if (e >= EP) return;
    int s, d;
    if (e < E_EDGES) { s = ei[e]; d = ei[E_EDGES + e]; }
    else { s = d = e - E_EDGES; }
    int p = atomicAdd(&curA[d], 1);
    colA[p] = s;
}

// ---------------- fused dual GEMM: xl = A@Wl + bl, xr = A@Wr + br ----------------
__device__ __forceinline__ float f4_get(const float4& v, int i) {
    return i == 0 ? v.x : i == 1 ? v.y : i == 2 ? v.z : v.w;
}

__global__ __launch_bounds__(256) void k_gemm(
    const float* __restrict__ A,
    const float* __restrict__ Wl, const float* __restrict__ bl,
    const float* __restrict__ Wr, const float* __restrict__ br,
    float* __restrict__ xl, float* __restrict__ xr, int M) {
    int t = threadIdx.x;
    int lane = t & 63;
    int wave = t >> 6;           // 0..3
    int rgrp = lane & 15;
    int cgrp = lane >> 4;        // 0..3
    int r0 = blockIdx.x * 64 + rgrp * 4;

    const float* W  = (wave < 2) ? Wl : Wr;
    const float* bb = (wave < 2) ? bl : br;
    float* O        = (wave < 2) ? xl : xr;
    int c0 = (wave & 1) * 64 + cgrp * 16;

    float acc[4][16];
#pragma unroll
    for (int i = 0; i < 4; i++)
#pragma unroll
        for (int j = 0; j < 16; j++) acc[i][j] = 0.f;

    int rr[4];
#pragma unroll
    for (int i = 0; i < 4; i++) {
        int r = r0 + i;
        rr[i] = (r < M) ? r : (M - 1);
    }

    for (int k = 0; k < 128; k += 4) {
        float4 a[4];
#pragma unroll
        for (int i = 0; i < 4; i++)
            a[i] = *(const float4*)&A[(size_t)rr[i] * 128 + k];
#pragma unroll
        for (int kk = 0; kk < 4; kk++) {
            float4 b0 = *(const float4*)&W[(k + kk) * 128 + c0];
            float4 b1 = *(const float4*)&W[(k + kk) * 128 + c0 + 4];
            float4 b2 = *(const float4*)&W[(k + kk) * 128 + c0 + 8];
            float4 b3 = *(const float4*)&W[(k + kk) * 128 + c0 + 12];
            float bv[16];
#pragma unroll
            for (int j = 0; j < 4; j++) {
                bv[j]      = f4_get(b0, j);
                bv[4 + j]  = f4_get(b1, j);
                bv[8 + j]  = f4_get(b2, j);
                bv[12 + j] = f4_get(b3, j);
            }
#pragma unroll
            for (int i = 0; i < 4; i++) {
                float av = f4_get(a[i], kk);
#pragma unroll
                for (int j = 0; j < 16; j++) acc[i][j] = fmaf(av, bv[j], acc[i][j]);
            }
        }
    }

    float4 bi[4];
#pragma unroll
    for (int j = 0; j < 4; j++) bi[j] = *(const float4*)&bb[c0 + 4 * j];
#pragma unroll
    for (int i = 0; i < 4; i++) {
        int r = r0 + i;
        if (r >= M) continue;
#pragma unroll
        for (int j = 0; j < 4; j++) {
            float4 o;
            o.x = acc[i][4 * j + 0] + f4_get(bi[j], 0);
            o.y = acc[i][4 * j + 1] + f4_get(bi[j], 1);
            o.z = acc[i][4 * j + 2] + f4_get(bi[j], 2);
            o.w = acc[i][4 * j + 3] + f4_get(bi[j], 3);
            *(float4*)&O[(size_t)r * 128 + c0 + 4 * j] = o;
        }
    }
}

// ---------------- fused edge softmax + aggregation: one wave per dst node ----------------
__global__ __launch_bounds__(256) void k_agg(
    const float* __restrict__ xl, const float* __restrict__ xr,
    const int* __restrict__ startA, const int* __restrict__ cnt,
    const int* __restrict__ colA, const float* __restrict__ att,
    const float* __restrict__ bias, float* __restrict__ out) {
    int wave = threadIdx.x >> 6;
    int lane = threadIdx.x & 63;
    int n = blockIdx.x * 4 + wave;
    if (n >= N_NODES) return;
    int c0 = lane * 2;

    float att0 = att[c0], att1 = att[c0 + 1];
    float2 xrv = *(const float2*)&xr[(size_t)n * 128 + c0];
    int s0 = startA[n];
    int cn = cnt[n];   // >= 1 (self loop)

    float acc0 = 0.f, acc1 = 0.f, wsum = 0.f;

    int myS = (lane < cn) ? colA[s0 + lane] : 0;
    int scur = __shfl(myS, 0, 64);
    float2 v = *(const float2*)&xl[(size_t)scur * 128 + c0];

    for (int j = 0; j < cn; ++j) {
        float2 vn = v;
        int jn = j + 1;
        if (jn < cn) {
            if ((jn & 63) == 0)
                myS = (jn + lane < cn) ? colA[s0 + jn + lane] : 0;
            int sn = __shfl(myS, jn & 63, 64);
            vn = *(const float2*)&xl[(size_t)sn * 128 + c0];
        }
        float e0 = v.x + xrv.x; e0 = (e0 > 0.f) ? e0 : NEG * e0;
        float e1 = v.y + xrv.y; e1 = (e1 > 0.f) ? e1 : NEG * e1;
        float p = e0 * att0 + e1 * att1;
        p += __shfl_xor(p, 1, 64);
        p += __shfl_xor(p, 2, 64);
        p += __shfl_xor(p, 4, 64);
        p += __shfl_xor(p, 8, 64);   // per-head (16-lane) sum
        float w = __expf(p);
        acc0 = fmaf(w, v.x, acc0);
        acc1 = fmaf(w, v.y, acc1);
        wsum += w;
        v = vn;
    }
    float inv = 1.f / wsum;
    float2 o;
    o.x = acc0 * inv + bias[c0];
    o.y = acc1 * inv + bias[c0 + 1];
    *(float2*)&out[(size_t)n * 128 + c0] = o;
}

// ---------------- BatchNorm stats / apply+ReLU ----------------
__global__ __launch_bounds__(256) void k_bnstats(const float* __restrict__ h,
                                                 float* __restrict__ gsum,
                                                 float* __restrict__ gsq) {
    int t = threadIdx.x;
    int c = t & 127;
    int half = t >> 7;
    float s = 0.f, q = 0.f;
    for (int r = blockIdx.x * 2 + half; r < N_NODES; r += gridDim.x * 2) {
        float v = h[(size_t)r * 128 + c];
        s += v;
        q = fmaf(v, v, q);
    }
    __shared__ float ls[256], lq[256];
    ls[t] = s; lq[t] = q;
    __syncthreads();
    if (t < 128) {
        atomicAdd(&gsum[c], ls[t] + ls[t + 128]);
        atomicAdd(&gsq[c],  lq[t] + lq[t + 128]);
    }
}

__global__ __launch_bounds__(256) void k_bnapply(float* __restrict__ h,
                                                 const float* __restrict__ gsum,
                                                 const float* __restrict__ gsq,
                                                 const float* __restrict__ g,
                                                 const float* __restrict__ be) {
    __shared__ float sc[128], sh[128];
    int t = threadIdx.x;
    if (t < 128) {
        float mu = gsum[t] * (1.f / N_NODES);
        float var = gsq[t] * (1.f / N_NODES) - mu * mu;
        float s = rsqrtf(var + EPS_BN) * g[t];
        sc[t] = s;
        sh[t] = be[t] - mu * s;
    }
    __syncthreads();
    size_t total = (size_t)N_NODES * 128 / 4;
    for (size_t i = blockIdx.x * 256 + t; i < total; i += (size_t)gridDim.x * 256) {
        float4 v = *(float4*)&h[i * 4];
        int cb = (int)((i * 4) & 127);
        v.x = fmaxf(fmaf(v.x, sc[cb + 0], sh[cb + 0]), 0.f);
        v.y = fmaxf(fmaf(v.y, sc[cb + 1], sh[cb + 1]), 0.f);
        v.z = fmaxf(fmaf(v.z, sc[cb + 2], sh[cb + 2]), 0.f);
        v.w = fmaxf(fmaf(v.w, sc[cb + 3], sh[cb + 3]), 0.f);
        *(float4*)&h[i * 4] = v;
    }
}

// ---------------- graph boundaries (batch is sorted) ----------------
__global__ void k_gstart(const int* __restrict__ batch, int* __restrict__ gstart) {
    int i = blockIdx.x * 256 + threadIdx.x;
    if (i >= N_NODES) return;
    int b = batch[i];
    int prev = (i == 0) ? -1 : batch[i - 1];
    for (int g = prev + 1; g <= b; g++) gstart[g] = i;
    if (i == N_NODES - 1)
        for (int g = b + 1; g <= NG; g++) gstart[g] = N_NODES;
}

// ---------------- mean pool + concat global_feat -> z [G,160] ----------------
__global__ __launch_bounds__(256) void k_pool(const float* __restrict__ h,
                                              const int* __restrict__ gstart,
                                              const float* __restrict__ gf,
                                              float* __restrict__ z) {
    int wave = threadIdx.x >> 6;
    int lane = threadIdx.x & 63;
    int g = blockIdx.x * 4 + wave;
    if (g >= NG) return;
    int r0 = gstart[g], r1 = gstart[g + 1];
    float s0 = 0.f, s1 = 0.f;
    for (int r = r0; r < r1; r++) {
        float2 v = *(const float2*)&h[(size_t)r * 128 + lane * 2];
        s0 += v.x; s1 += v.y;
    }
    float invc = 1.f / fmaxf((float)(r1 - r0), 1.f);
    float2 o; o.x = s0 * invc; o.y = s1 * invc;
    *(float2*)&z[(size_t)g * 160 + lane * 2] = o;
    if (lane < 16) {
        float2 gv = *(const float2*)&gf[(size_t)g * 32 + lane * 2];
        *(float2*)&z[(size_t)g * 160 + 128 + lane * 2] = gv;
    }
}

// ---------------- MLP head: relu(z@W1+b1)@W2+b2 -> out [G] ----------------
__global__ __launch_bounds__(256) void k_mlp(const float* __restrict__ z,
                                             const float* __restrict__ W1,
                                             const float* __restrict__ b1,
                                             const float* __restrict__ W2,
                                             const float* __restrict__ b2,
                                             float* __restrict__ out) {
    __shared__ float zs[160];
    __shared__ float red[4];
    int g = blockIdx.x;
    int t = threadIdx.x;
    if (t < 160) zs[t] = z[(size_t)g * 160 + t];
    __syncthreads();
    float acc = b1[t];
#pragma unroll 8
    for (int i = 0; i < 160; i++) acc = fmaf(zs[i], W1[i * 256 + t], acc);
    acc = fmaxf(acc, 0.f);
    float part = acc * W2[t];
    part += __shfl_xor(part, 32, 64);
    part += __shfl_xor(part, 16, 64);
    part += __shfl_xor(part, 8, 64);
    part += __shfl_xor(part, 4, 64);
    part += __shfl_xor(part, 2, 64);
    part += __shfl_xor(part, 1, 64);
    if ((t & 63) == 0) red[t >> 6] = part;
    __syncthreads();
    if (t == 0) out[g] = red[0] + red[1] + red[2] + red[3] + b2[0];
}

extern "C" void kernel_launch(void* const* d_in, const int* in_sizes, int n_in,
                              void* d_out, int out_size, void* d_ws, size_t ws_size,
                              hipStream_t stream) {
    (void)in_sizes; (void)n_in; (void)out_size; (void)ws_size;

    const float* x     = (const float*)d_in[0];
    const int*   ei    = (const int*)d_in[1];
    const int*   batch = (const int*)d_in[2];
    const float* gf    = (const float*)d_in[3];
    const float* Wl1 = (const float*)d_in[4];
    const float* bl1 = (const float*)d_in[5];
    const float* Wr1 = (const float*)d_in[6];
    const float* br1 = (const float*)d_in[7];
    const float* att1  = (const float*)d_in[8];
    const float* bias1 = (const float*)d_in[9];
    const float* g1  = (const float*)d_in[10];
    const float* be1 = (const float*)d_in[11];
    const float* Wl2 = (const float*)d_in[12];
    const float* bl2 = (const float*)d_in[13];
    const float* Wr2 = (const float*)d_in[14];
    const float* br2 = (const float*)d_in[15];
    const float* att2  = (const float*)d_in[16];
    const float* bias2 = (const float*)d_in[17];
    const float* g2  = (const float*)d_in[18];
    const float* be2 = (const float*)d_in[19];
    const float* Wfc1 = (const float*)d_in[20];
    const float* bfc1 = (const float*)d_in[21];
    const float* Wfc2 = (const float*)d_in[22];
    const float* bfc2 = (const float*)d_in[23];
    float* out = (float*)d_out;

    char* ws = (char*)d_ws;
    float* xl   = (float*)(ws + 0);
    float* xr   = (float*)(ws + 51200000);
    float* hbuf = (float*)(ws + 102400000);
    int*   colA = (int*)(ws + 153600000);
    int*   cnt  = (int*)(ws + 160400000);
    int*   cursor = (int*)(ws + 160800000);
    float* bnsum  = (float*)(ws + 160800256);   // 512 floats: sum1|sq1|sum2|sq2
    int*   startA = (int*)(ws + 160802304);
    int*   curA   = (int*)(ws + 161202304);
    int*   gstart = (int*)(ws + 161602304);
    float* z      = (float*)(ws + 161606656);

    // zero: cnt (400000 B) + cursor pad (256 B) + bnsum (2048 B)
    hipMemsetAsync(cnt, 0, 400000 + 256 + 2048, stream);

    // CSR build (shared by both layers) + graph boundaries
    k_count<<<(EP + 255) / 256, 256, 0, stream>>>(ei, cnt);
    k_gstart<<<(N_NODES + 255) / 256, 256, 0, stream>>>(batch, gstart);
    k_alloc<<<(N_NODES + 255) / 256, 256, 0, stream>>>(cnt, startA, curA, cursor);
    k_scatter<<<(EP + 255) / 256, 256, 0, stream>>>(ei, curA, colA);

    int gemm_grid = (N_NODES + 63) / 64;

    // Layer 1
    k_gemm<<<gemm_grid, 256, 0, stream>>>(x, Wl1, bl1, Wr1, br1, xl, xr, N_NODES);
    k_agg<<<(N_NODES + 3) / 4, 256, 0, stream>>>(xl, xr, startA, cnt, colA, att1, bias1, hbuf);
    k_bnstats<<<512, 256, 0, stream>>>(hbuf, bnsum + 0, bnsum + 128);
    k_bnapply<<<2048, 256, 0, stream>>>(hbuf, bnsum + 0, bnsum + 128, g1, be1);

    // Layer 2
    k_gemm<<<gemm_grid, 256, 0, stream>>>(hbuf, Wl2, bl2, Wr2, br2, xl, xr, N_NODES);
    k_agg<<<(N_NODES + 3) / 4, 256, 0, stream>>>(xl, xr, startA, cnt, colA, att2, bias2, hbuf);
    k_bnstats<<<512, 256, 0, stream>>>(hbuf, bnsum + 256, bnsum + 384);
    k_bnapply<<<2048, 256, 0, stream>>>(hbuf, bnsum + 256, bnsum + 384, g2, be2);

    // Pool + MLP
    k_pool<<<(NG + 3) / 4, 256, 0, stream>>>(hbuf, gstart, gf, z);
    k_mlp<<<NG, 256, 0, stream>>>(z, Wfc1, bfc1, Wfc2, bfc2, out);
}

// Round 2
// 975.115 us; speedup vs baseline: 1.1392x; 1.1392x over previous
//
#include <hip/hip_runtime.h>

#define N_NODES 100000
#define E_EDGES 1600000
#define EP (E_EDGES + N_NODES)
#define NG 1024
#define NEG 0.2f
#define EPS_BN 1e-5f

// ---------------- CSR build (by destination) ----------------
__global__ void k_count(const int* __restrict__ ei, int* __restrict__ cnt) {
    int e = blockIdx.x * 256 + threadIdx.x;
    if (e >= EP) return;
    int d = (e < E_EDGES) ? ei[E_EDGES + e] : (e - E_EDGES);
    atomicAdd(&cnt[d], 1);
}

__global__ void k_alloc(const int* __restrict__ cnt, int* __restrict__ startA,
                        int* __restrict__ curA, int* __restrict__ cursor) {
    int n = blockIdx.x * 256 + threadIdx.x;
    if (n >= N_NODES) return;
    int c = cnt[n];
    int s = atomicAdd(cursor, c);
    startA[n] = s;
    curA[n] = s;
}

__global__ void k_scatter(const int* __restrict__ ei, int* __restrict__ curA,
                          int* __restrict__ colA) {
    int e = blockIdx.x * 256 + threadIdx.x;
    if (e >= EP) return;
    int s, d;
    if (e < E_EDGES) { s = ei[e]; d = ei[E_EDGES + e]; }
    else { s = d = e - E_EDGES; }
    int p = atomicAdd(&curA[d], 1);
    colA[p] = s;
}

// ---------------- fused dual GEMM: xl = A@Wl + bl, xr = A@Wr + br ----------------
// LDS-staged, register-prefetch pipelined. Tile: 64 rows x (128 xl + 128 xr) cols.
// LDS per chunk (16 k): As[16][68] transposed A (4.25 KB) + Ws[2][16][128] (16 KB).
#define AS_STRIDE 68

__device__ __forceinline__ float f4_get(const float4& v, int i) {
    return i == 0 ? v.x : i == 1 ? v.y : i == 2 ? v.z : v.w;
}

__global__ __launch_bounds__(256) void k_gemm(
    const float* __restrict__ A,
    const float* __restrict__ Wl, const float* __restrict__ bl,
    const float* __restrict__ Wr, const float* __restrict__ br,
    float* __restrict__ xl, float* __restrict__ xr, int M) {
    __shared__ float As[16 * AS_STRIDE];
    __shared__ float Ws[2][16][128];

    int t = threadIdx.x;
    int lane = t & 63;
    int wave = t >> 6;           // 0..3
    int rgrp = lane & 15;
    int cgrp = lane >> 4;        // 0..3
    int brow = blockIdx.x * 64;
    int r0 = rgrp * 4;

    int mat = wave >> 1;                     // 0 = xl, 1 = xr
    int c0 = (wave & 1) * 64 + cgrp * 16;
    const float* bb = mat ? br : bl;
    float* O = mat ? xr : xl;

    // staging indices
    int arow = brow + (t >> 2);  arow = (arow < M) ? arow : (M - 1);
    int aq = t & 3;                          // k-quad within chunk
    int krow0 = t >> 5;                      // 0..7
    int wcol = (t & 31) * 4;

    float4 pa, pwl0, pwl1, pwr0, pwr1;

    // load chunk 0
    pa = *(const float4*)&A[(size_t)arow * 128 + aq * 4];
    pwl0 = *(const float4*)&Wl[(size_t)krow0 * 128 + wcol];
    pwl1 = *(const float4*)&Wl[(size_t)(krow0 + 8) * 128 + wcol];
    pwr0 = *(const float4*)&Wr[(size_t)krow0 * 128 + wcol];
    pwr1 = *(const float4*)&Wr[(size_t)(krow0 + 8) * 128 + wcol];
    // write chunk 0
#pragma unroll
    for (int j = 0; j < 4; j++) As[(aq * 4 + j) * AS_STRIDE + (t >> 2)] = f4_get(pa, j);
    *(float4*)&Ws[0][krow0][wcol] = pwl0;
    *(float4*)&Ws[0][krow0 + 8][wcol] = pwl1;
    *(float4*)&Ws[1][krow0][wcol] = pwr0;
    *(float4*)&Ws[1][krow0 + 8][wcol] = pwr1;
    __syncthreads();

    float acc[4][16];
#pragma unroll
    for (int i = 0; i < 4; i++)
#pragma unroll
        for (int j = 0; j < 16; j++) acc[i][j] = 0.f;

    for (int ch = 0; ch < 8; ++ch) {
        if (ch < 7) {
            int kc = (ch + 1) * 16;
            pa = *(const float4*)&A[(size_t)arow * 128 + kc + aq * 4];
            pwl0 = *(const float4*)&Wl[(size_t)(kc + krow0) * 128 + wcol];
            pwl1 = *(const float4*)&Wl[(size_t)(kc + krow0 + 8) * 128 + wcol];
            pwr0 = *(const float4*)&Wr[(size_t)(kc + krow0) * 128 + wcol];
            pwr1 = *(const float4*)&Wr[(size_t)(kc + krow0 + 8) * 128 + wcol];
        }
#pragma unroll
        for (int kk = 0; kk < 16; ++kk) {
            float4 a = *(const float4*)&As[kk * AS_STRIDE + r0];
            float4 w0 = *(const float4*)&Ws[mat][kk][c0];
            float4 w1 = *(const float4*)&Ws[mat][kk][c0 + 4];
            float4 w2 = *(const float4*)&Ws[mat][kk][c0 + 8];
            float4 w3 = *(const float4*)&Ws[mat][kk][c0 + 12];
            float bv[16];
#pragma unroll
            for (int j = 0; j < 4; j++) {
                bv[j]      = f4_get(w0, j);
                bv[4 + j]  = f4_get(w1, j);
                bv[8 + j]  = f4_get(w2, j);
                bv[12 + j] = f4_get(w3, j);
            }
#pragma unroll
            for (int i = 0; i < 4; i++) {
                float av = f4_get(a, i);
#pragma unroll
                for (int j = 0; j < 16; j++) acc[i][j] = fmaf(av, bv[j], acc[i][j]);
            }
        }
        __syncthreads();
        if (ch < 7) {
#pragma unroll
            for (int j = 0; j < 4; j++) As[(aq * 4 + j) * AS_STRIDE + (t >> 2)] = f4_get(pa, j);
            *(float4*)&Ws[0][krow0][wcol] = pwl0;
            *(float4*)&Ws[0][krow0 + 8][wcol] = pwl1;
            *(float4*)&Ws[1][krow0][wcol] = pwr0;
            *(float4*)&Ws[1][krow0 + 8][wcol] = pwr1;
            __syncthreads();
        }
    }

    float4 bi[4];
#pragma unroll
    for (int j = 0; j < 4; j++) bi[j] = *(const float4*)&bb[c0 + 4 * j];
#pragma unroll
    for (int i = 0; i < 4; i++) {
        int r = brow + r0 + i;
        if (r >= M) continue;
#pragma unroll
        for (int j = 0; j < 4; j++) {
            float4 o;
            o.x = acc[i][4 * j + 0] + f4_get(bi[j], 0);
            o.y = acc[i][4 * j + 1] + f4_get(bi[j], 1);
            o.z = acc[i][4 * j + 2] + f4_get(bi[j], 2);
            o.w = acc[i][4 * j + 3] + f4_get(bi[j], 3);
            *(float4*)&O[(size_t)r * 128 + c0 + 4 * j] = o;
        }
    }
}

// NOTE on As layout: As[k][row] with stride 68 floats. Compute read:
// lanes rgrp=0..15 read words k*68 + 4*rgrp .. +3 -> 64 consecutive words
// -> 2 lanes/bank (free, m136). Transposed write: banks (16kq+4j+row)%32 -> 2-way.

// ---------------- fused edge softmax + aggregation: one wave per dst node ----------------
// Depth-2 software pipeline over edges to hide L2/L3 gather latency.
__global__ __launch_bounds__(256) void k_agg(
    const float* __restrict__ xl, const float* __restrict__ xr,
    const int* __restrict__ startA, const int* __restrict__ cnt,
    const int* __restrict__ colA, const float* __restrict__ att,
    const float* __restrict__ bias, float* __restrict__ out) {
    int wave = threadIdx.x >> 6;
    int lane = threadIdx.x & 63;
    int n = blockIdx.x * 4 + wave;
    if (n >= N_NODES) return;
    int c0 = lane * 2;

    float att0 = att[c0], att1 = att[c0 + 1];
    float2 xrv = *(const float2*)&xr[(size_t)n * 128 + c0];
    int s0 = startA[n];
    int cn = cnt[n];   // >= 1 (self loop)

    float acc0 = 0.f, acc1 = 0.f, wsum = 0.f;

    int myS = (lane < cn) ? colA[s0 + lane] : 0;
    float2 v0, v1;
    {
        int s = __shfl(myS, 0, 64);
        v0 = *(const float2*)&xl[(size_t)s * 128 + c0];
    }
    v1 = v0;
    if (cn > 1) {
        int s = __shfl(myS, 1, 64);
        v1 = *(const float2*)&xl[(size_t)s * 128 + c0];
    }

    for (int j = 0; j < cn; ++j) {
        float2 v2 = v1;
        int jn = j + 2;
        if (jn < cn) {
            if ((jn & 63) == 0)
                myS = (jn + lane < cn) ? colA[s0 + jn + lane] : 0;
            int s = __shfl(myS, jn & 63, 64);
            v2 = *(const float2*)&xl[(size_t)s * 128 + c0];
        }
        float e0 = v0.x + xrv.x; e0 = (e0 > 0.f) ? e0 : NEG * e0;
        float e1 = v0.y + xrv.y; e1 = (e1 > 0.f) ? e1 : NEG * e1;
        float p = e0 * att0 + e1 * att1;
        p += __shfl_xor(p, 1, 64);
        p += __shfl_xor(p, 2, 64);
        p += __shfl_xor(p, 4, 64);
        p += __shfl_xor(p, 8, 64);   // per-head (16-lane) sum
        float w = __expf(p);
        acc0 = fmaf(w, v0.x, acc0);
        acc1 = fmaf(w, v0.y, acc1);
        wsum += w;
        v0 = v1;
        v1 = v2;
    }
    float inv = 1.f / wsum;
    float2 o;
    o.x = acc0 * inv + bias[c0];
    o.y = acc1 * inv + bias[c0 + 1];
    *(float2*)&out[(size_t)n * 128 + c0] = o;
}

// ---------------- BatchNorm stats / apply+ReLU ----------------
__global__ __launch_bounds__(256) void k_bnstats(const float* __restrict__ h,
                                                 float* __restrict__ gsum,
                                                 float* __restrict__ gsq) {
    int t = threadIdx.x;
    int c = t & 127;
    int half = t >> 7;
    float s = 0.f, q = 0.f;
    for (int r = blockIdx.x * 2 + half; r < N_NODES; r += gridDim.x * 2) {
        float v = h[(size_t)r * 128 + c];
        s += v;
        q = fmaf(v, v, q);
    }
    __shared__ float ls[256], lq[256];
    ls[t] = s; lq[t] = q;
    __syncthreads();
    if (t < 128) {
        atomicAdd(&gsum[c], ls[t] + ls[t + 128]);
        atomicAdd(&gsq[c],  lq[t] + lq[t + 128]);
    }
}

__global__ __launch_bounds__(256) void k_bnapply(float* __restrict__ h,
                                                 const float* __restrict__ gsum,
                                                 const float* __restrict__ gsq,
                                                 const float* __restrict__ g,
                                                 const float* __restrict__ be) {
    __shared__ float sc[128], sh[128];
    int t = threadIdx.x;
    if (t < 128) {
        float mu = gsum[t] * (1.f / N_NODES);
        float var = gsq[t] * (1.f / N_NODES) - mu * mu;
        float s = rsqrtf(var + EPS_BN) * g[t];
        sc[t] = s;
        sh[t] = be[t] - mu * s;
    }
    __syncthreads();
    size_t total = (size_t)N_NODES * 128 / 4;
    for (size_t i = blockIdx.x * 256 + t; i < total; i += (size_t)gridDim.x * 256) {
        float4 v = *(float4*)&h[i * 4];
        int cb = (int)((i * 4) & 127);
        v.x = fmaxf(fmaf(v.x, sc[cb + 0], sh[cb + 0]), 0.f);
        v.y = fmaxf(fmaf(v.y, sc[cb + 1], sh[cb + 1]), 0.f);
        v.z = fmaxf(fmaf(v.z, sc[cb + 2], sh[cb + 2]), 0.f);
        v.w = fmaxf(fmaf(v.w, sc[cb + 3], sh[cb + 3]), 0.f);
        *(float4*)&h[i * 4] = v;
    }
}

// ---------------- graph boundaries (batch is sorted) ----------------
__global__ void k_gstart(const int* __restrict__ batch, int* __restrict__ gstart) {
    int i = blockIdx.x * 256 + threadIdx.x;
    if (i >= N_NODES) return;
    int b = batch[i];
    int prev = (i == 0) ? -1 : batch[i - 1];
    for (int g = prev + 1; g <= b; g++) gstart[g] = i;
    if (i == N_NODES - 1)
        for (int g = b + 1; g <= NG; g++) gstart[g] = N_NODES;
}

// ---------------- mean pool + concat global_feat -> z [G,160] ----------------
__global__ __launch_bounds__(256) void k_pool(const float* __restrict__ h,
                                              const int* __restrict__ gstart,
                                              const float* __restrict__ gf,
                                              float* __restrict__ z) {
    int wave = threadIdx.x >> 6;
    int lane = threadIdx.x & 63;
    int g = blockIdx.x * 4 + wave;
    if (g >= NG) return;
    int r0 = gstart[g], r1 = gstart[g + 1];
    float s0 = 0.f, s1 = 0.f;
    for (int r = r0; r < r1; r++) {
        float2 v = *(const float2*)&h[(size_t)r * 128 + lane * 2];
        s0 += v.x; s1 += v.y;
    }
    float invc = 1.f / fmaxf((float)(r1 - r0), 1.f);
    float2 o; o.x = s0 * invc; o.y = s1 * invc;
    *(float2*)&z[(size_t)g * 160 + lane * 2] = o;
    if (lane < 16) {
        float2 gv = *(const float2*)&gf[(size_t)g * 32 + lane * 2];
        *(float2*)&z[(size_t)g * 160 + 128 + lane * 2] = gv;
    }
}

// ---------------- MLP head: relu(z@W1+b1)@W2+b2 -> out [G] ----------------
__global__ __launch_bounds__(256) void k_mlp(const float* __restrict__ z,
                                             const float* __restrict__ W1,
                                             const float* __restrict__ b1,
                                             const float* __restrict__ W2,
                                             const float* __restrict__ b2,
                                             float* __restrict__ out) {
    __shared__ float zs[160];
    __shared__ float red[4];
    int g = blockIdx.x;
    int t = threadIdx.x;
    if (t < 160) zs[t] = z[(size_t)g * 160 + t];
    __syncthreads();
    float acc = b1[t];
#pragma unroll 8
    for (int i = 0; i < 160; i++) acc = fmaf(zs[i], W1[i * 256 + t], acc);
    acc = fmaxf(acc, 0.f);
    float part = acc * W2[t];
    part += __shfl_xor(part, 32, 64);
    part += __shfl_xor(part, 16, 64);
    part += __shfl_xor(part, 8, 64);
    part += __shfl_xor(part, 4, 64);
    part += __shfl_xor(part, 2, 64);
    part += __shfl_xor(part, 1, 64);
    if ((t & 63) == 0) red[t >> 6] = part;
    __syncthreads();
    if (t == 0) out[g] = red[0] + red[1] + red[2] + red[3] + b2[0];
}

extern "C" void kernel_launch(void* const* d_in, const int* in_sizes, int n_in,
                              void* d_out, int out_size, void* d_ws, size_t ws_size,
                              hipStream_t stream) {
    (void)in_sizes; (void)n_in; (void)out_size; (void)ws_size;

    const float* x     = (const float*)d_in[0];
    const int*   ei    = (const int*)d_in[1];
    const int*   batch = (const int*)d_in[2];
    const float* gf    = (const float*)d_in[3];
    const float* Wl1 = (const float*)d_in[4];
    const float* bl1 = (const float*)d_in[5];
    const float* Wr1 = (const float*)d_in[6];
    const float* br1 = (const float*)d_in[7];
    const float* att1  = (const float*)d_in[8];
    const float* bias1 = (const float*)d_in[9];
    const float* g1  = (const float*)d_in[10];
    const float* be1 = (const float*)d_in[11];
    const float* Wl2 = (const float*)d_in[12];
    const float* bl2 = (const float*)d_in[13];
    const float* Wr2 = (const float*)d_in[14];
    const float* br2 = (const float*)d_in[15];
    const float* att2  = (const float*)d_in[16];
    const float* bias2 = (const float*)d_in[17];
    const float* g2  = (const float*)d_in[18];
    const float* be2 = (const float*)d_in[19];
    const float* Wfc1 = (const float*)d_in[20];
    const float* bfc1 = (const float*)d_in[21];
    const float* Wfc2 = (const float*)d_in[22];
    const float* bfc2 = (const float*)d_in[23];
    float* out = (float*)d_out;

    char* ws = (char*)d_ws;
    float* xl   = (float*)(ws + 0);
    float* xr   = (float*)(ws + 51200000);
    float* hbuf = (float*)(ws + 102400000);
    int*   colA = (int*)(ws + 153600000);
    int*   cnt  = (int*)(ws + 160400000);
    int*   cursor = (int*)(ws + 160800000);
    float* bnsum  = (float*)(ws + 160800256);   // 512 floats: sum1|sq1|sum2|sq2
    int*   startA = (int*)(ws + 160802304);
    int*   curA   = (int*)(ws + 161202304);
    int*   gstart = (int*)(ws + 161602304);
    float* z      = (float*)(ws + 161606656);

    // zero: cnt (400000 B) + cursor pad (256 B) + bnsum (2048 B)
    hipMemsetAsync(cnt, 0, 400000 + 256 + 2048, stream);

    // CSR build (shared by both layers) + graph boundaries
    k_count<<<(EP + 255) / 256, 256, 0, stream>>>(ei, cnt);
    k_gstart<<<(N_NODES + 255) / 256, 256, 0, stream>>>(batch, gstart);
    k_alloc<<<(N_NODES + 255) / 256, 256, 0, stream>>>(cnt, startA, curA, cursor);
    k_scatter<<<(EP + 255) / 256, 256, 0, stream>>>(ei, curA, colA);

    int gemm_grid = (N_NODES + 63) / 64;

    // Layer 1
    k_gemm<<<gemm_grid, 256, 0, stream>>>(x, Wl1, bl1, Wr1, br1, xl, xr, N_NODES);
    k_agg<<<(N_NODES + 3) / 4, 256, 0, stream>>>(xl, xr, startA, cnt, colA, att1, bias1, hbuf);
    k_bnstats<<<512, 256, 0, stream>>>(hbuf, bnsum + 0, bnsum + 128);
    k_bnapply<<<2048, 256, 0, stream>>>(hbuf, bnsum + 0, bnsum + 128, g1, be1);

    // Layer 2
    k_gemm<<<gemm_grid, 256, 0, stream>>>(hbuf, Wl2, bl2, Wr2, br2, xl, xr, N_NODES);
    k_agg<<<(N_NODES + 3) / 4, 256, 0, stream>>>(xl, xr, startA, cnt, colA, att2, bias2, hbuf);
    k_bnstats<<<512, 256, 0, stream>>>(hbuf, bnsum + 256, bnsum + 384);
    k_bnapply<<<2048, 256, 0, stream>>>(hbuf, bnsum + 256, bnsum + 384, g2, be2);

    // Pool + MLP
    k_pool<<<(NG + 3) / 4, 256, 0, stream>>>(hbuf, gstart, gf, z);
    k_mlp<<<NG, 256, 0, stream>>>(z, Wfc1, bfc1, Wfc2, bfc2, out);
}

// Round 3
// 659.105 us; speedup vs baseline: 1.6854x; 1.4795x over previous
//
#include <hip/hip_runtime.h>

#define N_NODES 100000
#define E_EDGES 1600000
#define EP (E_EDGES + N_NODES)
#define NG 1024
#define NEG 0.2f
#define EPS_BN 1e-5f

typedef __attribute__((ext_vector_type(8))) short bf8_t;   // 8 bf16 = 4 VGPR (MFMA A/B operand)
typedef __attribute__((ext_vector_type(4))) float f4_t;    // MFMA C/D operand

__device__ __forceinline__ unsigned short f2b(float f) {   // f32 -> bf16 RNE
    unsigned u = __float_as_uint(f);
    u += 0x7FFF + ((u >> 16) & 1);
    return (unsigned short)(u >> 16);
}

// ---------------- CSR build (by destination) ----------------
__global__ void k_count(const int* __restrict__ ei, int* __restrict__ cnt) {
    int e = blockIdx.x * 256 + threadIdx.x;
    if (e >= EP) return;
    int d = (e < E_EDGES) ? ei[E_EDGES + e] : (e - E_EDGES);
    atomicAdd(&cnt[d], 1);
}

__global__ void k_alloc(const int* __restrict__ cnt, int* __restrict__ startA,
                        int* __restrict__ curA, int* __restrict__ cursor) {
    int n = blockIdx.x * 256 + threadIdx.x;
    if (n >= N_NODES) return;
    int c = cnt[n];
    int s = atomicAdd(cursor, c);
    startA[n] = s;
    curA[n] = s;
}

__global__ void k_scatter(const int* __restrict__ ei, int* __restrict__ curA,
                          int* __restrict__ colA) {
    int e = blockIdx.x * 256 + threadIdx.x;
    if (e >= EP) return;
    int s, d;
    if (e < E_EDGES) { s = ei[e]; d = ei[E_EDGES + e]; }
    else { s = d = e - E_EDGES; }
    int p = atomicAdd(&curA[d], 1);
    colA[p] = s;
}

// ---------------- MFMA dual GEMM: xl = A@Wl + bl, xr = A@Wr + br (bf16 out) --------
// Block: 256 thr = 4 waves; tile 64 rows x 256 out cols (xl|xr). Wave w: mat=w>>1,
// col half = (w&1)*64, 4x4 grid of 16x16 frags, K=128 in 4 steps of 32.
// LDS 80KiB: As 64x128 bf16 (16K) + Wt[2][128n][128k] bf16 transposed (64K),
// both XOR-swizzled byte^=(row&7)<<4 to kill stride-256B bank conflicts (G4).
// Optional fused input transform: A := relu(A*sc[k]+sh[k])  (BN apply of prev layer).
template<bool AFF>
__global__ __launch_bounds__(256) void k_gemm(
    const float* __restrict__ A,
    const float* __restrict__ Wl, const float* __restrict__ bl,
    const float* __restrict__ Wr, const float* __restrict__ br,
    const float* __restrict__ sc, const float* __restrict__ sh,
    unsigned short* __restrict__ xl, unsigned short* __restrict__ xr, int M)
{
    __shared__ char lds[81920];
    short* As = (short*)lds;             // 16384 B
    short* Wt = (short*)(lds + 16384);   // 65536 B

    int t = threadIdx.x;
    int lane = t & 63;
    int w = t >> 6;
    int brow = blockIdx.x * 64;

    // ---- stage A (convert +optional affine+relu) ----
    {
        int kbase = (t & 7) * 16;
        float scv[16], shv[16];
        if (AFF) {
#pragma unroll
            for (int q = 0; q < 4; ++q) {
                float4 a4 = *(const float4*)&sc[kbase + q * 4];
                float4 b4 = *(const float4*)&sh[kbase + q * 4];
                scv[q*4+0]=a4.x; scv[q*4+1]=a4.y; scv[q*4+2]=a4.z; scv[q*4+3]=a4.w;
                shv[q*4+0]=b4.x; shv[q*4+1]=b4.y; shv[q*4+2]=b4.z; shv[q*4+3]=b4.w;
            }
        }
#pragma unroll
        for (int p = 0; p < 2; ++p) {
            int row = p * 32 + (t >> 3);
            int ar = brow + row; if (ar >= M) ar = M - 1;
            const float* src = &A[(size_t)ar * 128 + kbase];
            unsigned short vb[16];
#pragma unroll
            for (int q = 0; q < 4; ++q) {
                float4 x4 = *(const float4*)&src[q * 4];
                float vv[4] = {x4.x, x4.y, x4.z, x4.w};
#pragma unroll
                for (int e = 0; e < 4; ++e) {
                    float f = vv[e];
                    if (AFF) f = fmaxf(fmaf(f, scv[q*4+e], shv[q*4+e]), 0.f);
                    vb[q * 4 + e] = f2b(f);
                }
            }
            int swz = (row & 7) << 4;
#pragma unroll
            for (int u = 0; u < 2; ++u) {
                int off = (row * 256 + kbase * 2 + u * 16) ^ swz;
                *(int4*)((char*)As + off) = *(int4*)&vb[u * 8];
            }
        }
    }

    // ---- stage W transposed (Wt[n][k], bf16) ----
#pragma unroll
    for (int m = 0; m < 2; ++m) {
        const float* Wm = m ? Wr : Wl;
        char* Wtm = (char*)Wt + m * 32768;
#pragma unroll
        for (int r = 0; r < 4; ++r) {
            int idx = r * 256 + t;
            int kb = (idx >> 5) * 4;
            int nb = (idx & 31) * 4;
            float4 r0 = *(const float4*)&Wm[(size_t)(kb + 0) * 128 + nb];
            float4 r1 = *(const float4*)&Wm[(size_t)(kb + 1) * 128 + nb];
            float4 r2 = *(const float4*)&Wm[(size_t)(kb + 2) * 128 + nb];
            float4 r3 = *(const float4*)&Wm[(size_t)(kb + 3) * 128 + nb];
            float cols[4][4] = {{r0.x, r1.x, r2.x, r3.x},
                                {r0.y, r1.y, r2.y, r3.y},
                                {r0.z, r1.z, r2.z, r3.z},
                                {r0.w, r1.w, r2.w, r3.w}};
#pragma unroll
            for (int i2 = 0; i2 < 4; ++i2) {
                int n = nb + i2;
                ushort4 wv;
                wv.x = f2b(cols[i2][0]); wv.y = f2b(cols[i2][1]);
                wv.z = f2b(cols[i2][2]); wv.w = f2b(cols[i2][3]);
                int off = (n * 256 + kb * 2) ^ ((n & 7) << 4);
                *(ushort4*)(Wtm + off) = wv;
            }
        }
    }
    __syncthreads();

    // ---- compute ----
    int rl = lane & 15;
    int kh = lane >> 4;
    int mat = w >> 1;
    int c0 = (w & 1) * 64;
    int swz = (rl & 7) << 4;

    f4_t acc[4][4];
#pragma unroll
    for (int i = 0; i < 4; ++i)
#pragma unroll
        for (int j = 0; j < 4; ++j) { f4_t z = {0.f,0.f,0.f,0.f}; acc[i][j] = z; }

    const char* Asc = (const char*)As;
    const char* Wtc = (const char*)Wt + mat * 32768;

#pragma unroll
    for (int s = 0; s < 4; ++s) {
        int kb2 = (s * 32 + kh * 8) * 2;
        bf8_t af[4], bfr[4];
#pragma unroll
        for (int i = 0; i < 4; ++i) {
            int row = 16 * i + rl;
            af[i] = *(const bf8_t*)(Asc + ((row * 256 + kb2) ^ swz));
        }
#pragma unroll
        for (int j = 0; j < 4; ++j) {
            int n = c0 + 16 * j + rl;
            bfr[j] = *(const bf8_t*)(Wtc + ((n * 256 + kb2) ^ swz));
        }
#pragma unroll
        for (int i = 0; i < 4; ++i)
#pragma unroll
            for (int j = 0; j < 4; ++j)
                acc[i][j] = __builtin_amdgcn_mfma_f32_16x16x32_bf16(af[i], bfr[j], acc[i][j], 0, 0, 0);
    }

    // ---- epilogue: bias + bf16, bounce through LDS for coalesced stores ----
    __syncthreads();
    short* Cs = (short*)lds;   // [64][256] bf16, swizzled
    const float* bb = mat ? br : bl;
    float blv[4];
#pragma unroll
    for (int j = 0; j < 4; ++j) blv[j] = bb[c0 + 16 * j + rl];
    int colbase = mat * 128 + c0;
#pragma unroll
    for (int i = 0; i < 4; ++i)
#pragma unroll
        for (int j = 0; j < 4; ++j) {
            int col = colbase + 16 * j + rl;
#pragma unroll
            for (int q = 0; q < 4; ++q) {
                int row = 16 * i + kh * 4 + q;
                int off = (row * 512 + col * 2) ^ ((row & 7) << 4);
                *(short*)((char*)Cs + off) = (short)f2b(acc[i][j][q] + blv[j]);
            }
        }
    __syncthreads();
#pragma unroll
    for (int rep = 0; rep < 8; ++rep) {
        int unit = rep * 256 + t;
        int row = unit >> 5;
        int slot = unit & 31;
        int gr = brow + row;
        if (gr < M) {
            int off = (row * 512 + slot * 16) ^ ((row & 7) << 4);
            int4 vv = *(const int4*)((char*)Cs + off);
            unsigned short* O = (slot < 16) ? xl : xr;
            int gcol = (slot & 15) * 8;
            *(int4*)&O[(size_t)gr * 128 + gcol] = vv;
        }
    }
}

// ---------------- fused edge softmax + aggregation (bf16 gather) ----------------
__global__ __launch_bounds__(256) void k_agg(
    const unsigned* __restrict__ xl, const unsigned* __restrict__ xr,
    const int* __restrict__ startA, const int* __restrict__ cnt,
    const int* __restrict__ colA, const float* __restrict__ att,
    const float* __restrict__ bias, float* __restrict__ out) {
    int wave = threadIdx.x >> 6;
    int lane = threadIdx.x & 63;
    int n = blockIdx.x * 4 + wave;
    if (n >= N_NODES) return;
    int c0 = lane * 2;

    float att0 = att[c0], att1 = att[c0 + 1];
    unsigned uxr = xr[(size_t)n * 64 + lane];
    float xr0 = __uint_as_float(uxr << 16);
    float xr1 = __uint_as_float(uxr & 0xFFFF0000u);
    int s0 = startA[n];
    int cn = cnt[n];   // >= 1 (self loop)

    float acc0 = 0.f, acc1 = 0.f, wsum = 0.f;

    int myS = (lane < cn) ? colA[s0 + lane] : 0;
    unsigned u0, u1;
    {
        int s = __shfl(myS, 0, 64);
        u0 = xl[(size_t)s * 64 + lane];
    }
    u1 = u0;
    if (cn > 1) {
        int s = __shfl(myS, 1, 64);
        u1 = xl[(size_t)s * 64 + lane];
    }

    for (int j = 0; j < cn; ++j) {
        unsigned u2 = u1;
        int jn = j + 2;
        if (jn < cn) {
            if ((jn & 63) == 0)
                myS = (jn + lane < cn) ? colA[s0 + jn + lane] : 0;
            int s = __shfl(myS, jn & 63, 64);
            u2 = xl[(size_t)s * 64 + lane];
        }
        float v0 = __uint_as_float(u0 << 16);
        float v1 = __uint_as_float(u0 & 0xFFFF0000u);
        float e0 = v0 + xr0; e0 = (e0 > 0.f) ? e0 : NEG * e0;
        float e1 = v1 + xr1; e1 = (e1 > 0.f) ? e1 : NEG * e1;
        float p = e0 * att0 + e1 * att1;
        p += __shfl_xor(p, 1, 64);
        p += __shfl_xor(p, 2, 64);
        p += __shfl_xor(p, 4, 64);
        p += __shfl_xor(p, 8, 64);   // per-head (16-lane) sum
        float wgt = __expf(p);
        acc0 = fmaf(wgt, v0, acc0);
        acc1 = fmaf(wgt, v1, acc1);
        wsum += wgt;
        u0 = u1;
        u1 = u2;
    }
    float inv = 1.f / wsum;
    float2 o;
    o.x = acc0 * inv + bias[c0];
    o.y = acc1 * inv + bias[c0 + 1];
    *(float2*)&out[(size_t)n * 128 + c0] = o;
}

// ---------------- BatchNorm stats + finalize ----------------
__global__ __launch_bounds__(256) void k_bnstats(const float* __restrict__ h,
                                                 float* __restrict__ gsum,
                                                 float* __restrict__ gsq) {
    int t = threadIdx.x;
    int c = t & 127;
    int half = t >> 7;
    float s = 0.f, q = 0.f;
    for (int r = blockIdx.x * 2 + half; r < N_NODES; r += gridDim.x * 2) {
        float v = h[(size_t)r * 128 + c];
        s += v;
        q = fmaf(v, v, q);
    }
    __shared__ float ls[256], lq[256];
    ls[t] = s; lq[t] = q;
    __syncthreads();
    if (t < 128) {
        atomicAdd(&gsum[c], ls[t] + ls[t + 128]);
        atomicAdd(&gsq[c],  lq[t] + lq[t + 128]);
    }
}

__global__ void k_bnfinal(const float* __restrict__ gsum, const float* __restrict__ gsq,
                          const float* __restrict__ g, const float* __restrict__ be,
                          float* __restrict__ sc, float* __restrict__ sh) {
    int c = threadIdx.x;   // 128
    float mu = gsum[c] * (1.f / N_NODES);
    float var = gsq[c] * (1.f / N_NODES) - mu * mu;
    float s = rsqrtf(var + EPS_BN) * g[c];
    sc[c] = s;
    sh[c] = be[c] - mu * s;
}

// ---------------- graph boundaries (batch is sorted) ----------------
__global__ void k_gstart(const int* __restrict__ batch, int* __restrict__ gstart) {
    int i = blockIdx.x * 256 + threadIdx.x;
    if (i >= N_NODES) return;
    int b = batch[i];
    int prev = (i == 0) ? -1 : batch[i - 1];
    for (int g = prev + 1; g <= b; g++) gstart[g] = i;
    if (i == N_NODES - 1)
        for (int g = b + 1; g <= NG; g++) gstart[g] = N_NODES;
}

// ---------------- mean pool (with fused BN2 affine+relu) + concat -> z [G,160] ----
__global__ __launch_bounds__(256) void k_pool(const float* __restrict__ h,
                                              const int* __restrict__ gstart,
                                              const float* __restrict__ gf,
                                              const float* __restrict__ sc,
                                              const float* __restrict__ sh,
                                              float* __restrict__ z) {
    int wave = threadIdx.x >> 6;
    int lane = threadIdx.x & 63;
    int g = blockIdx.x * 4 + wave;
    if (g >= NG) return;
    int c0 = lane * 2;
    float sc0 = sc[c0], sc1 = sc[c0 + 1], sh0 = sh[c0], sh1 = sh[c0 + 1];
    int r0 = gstart[g], r1 = gstart[g + 1];
    float s0 = 0.f, s1 = 0.f;
    for (int r = r0; r < r1; r++) {
        float2 v = *(const float2*)&h[(size_t)r * 128 + c0];
        s0 += fmaxf(fmaf(v.x, sc0, sh0), 0.f);
        s1 += fmaxf(fmaf(v.y, sc1, sh1), 0.f);
    }
    float invc = 1.f / fmaxf((float)(r1 - r0), 1.f);
    float2 o; o.x = s0 * invc; o.y = s1 * invc;
    *(float2*)&z[(size_t)g * 160 + c0] = o;
    if (lane < 16) {
        float2 gv = *(const float2*)&gf[(size_t)g * 32 + lane * 2];
        *(float2*)&z[(size_t)g * 160 + 128 + lane * 2] = gv;
    }
}

// ---------------- MLP head ----------------
__global__ __launch_bounds__(256) void k_mlp(const float* __restrict__ z,
                                             const float* __restrict__ W1,
                                             const float* __restrict__ b1,
                                             const float* __restrict__ W2,
                                             const float* __restrict__ b2,
                                             float* __restrict__ out) {
    __shared__ float zs[160];
    __shared__ float red[4];
    int g = blockIdx.x;
    int t = threadIdx.x;
    if (t < 160) zs[t] = z[(size_t)g * 160 + t];
    __syncthreads();
    float acc = b1[t];
#pragma unroll 8
    for (int i = 0; i < 160; i++) acc = fmaf(zs[i], W1[i * 256 + t], acc);
    acc = fmaxf(acc, 0.f);
    float part = acc * W2[t];
    part += __shfl_xor(part, 32, 64);
    part += __shfl_xor(part, 16, 64);
    part += __shfl_xor(part, 8, 64);
    part += __shfl_xor(part, 4, 64);
    part += __shfl_xor(part, 2, 64);
    part += __shfl_xor(part, 1, 64);
    if ((t & 63) == 0) red[t >> 6] = part;
    __syncthreads();
    if (t == 0) out[g] = red[0] + red[1] + red[2] + red[3] + b2[0];
}

extern "C" void kernel_launch(void* const* d_in, const int* in_sizes, int n_in,
                              void* d_out, int out_size, void* d_ws, size_t ws_size,
                              hipStream_t stream) {
    (void)in_sizes; (void)n_in; (void)out_size; (void)ws_size;

    const float* x     = (const float*)d_in[0];
    const int*   ei    = (const int*)d_in[1];
    const int*   batch = (const int*)d_in[2];
    const float* gf    = (const float*)d_in[3];
    const float* Wl1 = (const float*)d_in[4];
    const float* bl1 = (const float*)d_in[5];
    const float* Wr1 = (const float*)d_in[6];
    const float* br1 = (const float*)d_in[7];
    const float* att1  = (const float*)d_in[8];
    const float* bias1 = (const float*)d_in[9];
    const float* g1  = (const float*)d_in[10];
    const float* be1 = (const float*)d_in[11];
    const float* Wl2 = (const float*)d_in[12];
    const float* bl2 = (const float*)d_in[13];
    const float* Wr2 = (const float*)d_in[14];
    const float* br2 = (const float*)d_in[15];
    const float* att2  = (const float*)d_in[16];
    const float* bias2 = (const float*)d_in[17];
    const float* g2  = (const float*)d_in[18];
    const float* be2 = (const float*)d_in[19];
    const float* Wfc1 = (const float*)d_in[20];
    const float* bfc1 = (const float*)d_in[21];
    const float* Wfc2 = (const float*)d_in[22];
    const float* bfc2 = (const float*)d_in[23];
    float* out = (float*)d_out;

    char* ws = (char*)d_ws;
    unsigned short* xl = (unsigned short*)(ws + 0);           // 25.6 MB bf16
    unsigned short* xr = (unsigned short*)(ws + 25600000);    // 25.6 MB bf16
    float* h      = (float*)(ws + 51200000);                  // 51.2 MB f32
    int*   colA   = (int*)(ws + 102400000);
    int*   cnt    = (int*)(ws + 109200000);
    int*   cursor = (int*)(ws + 109600000);
    float* bnsum  = (float*)(ws + 109600256);   // 512 f32: sum1|sq1|sum2|sq2
    float* scsh   = (float*)(ws + 109602304);   // 512 f32: sc1|sh1|sc2|sh2
    int*   startA = (int*)(ws + 109604352);
    int*   curA   = (int*)(ws + 110004352);
    int*   gstart = (int*)(ws + 110404352);
    float* z      = (float*)(ws + 110420992);

    // zero: cnt (400000) + cursor (256) + bnsum (2048) — contiguous
    hipMemsetAsync(cnt, 0, 400000 + 256 + 2048, stream);

    // CSR build (shared by both layers) + graph boundaries
    k_count<<<(EP + 255) / 256, 256, 0, stream>>>(ei, cnt);
    k_gstart<<<(N_NODES + 255) / 256, 256, 0, stream>>>(batch, gstart);
    k_alloc<<<(N_NODES + 255) / 256, 256, 0, stream>>>(cnt, startA, curA, cursor);
    k_scatter<<<(EP + 255) / 256, 256, 0, stream>>>(ei, curA, colA);

    int gemm_grid = (N_NODES + 63) / 64;

    // Layer 1
    k_gemm<false><<<gemm_grid, 256, 0, stream>>>(x, Wl1, bl1, Wr1, br1,
                                                 nullptr, nullptr, xl, xr, N_NODES);
    k_agg<<<(N_NODES + 3) / 4, 256, 0, stream>>>((const unsigned*)xl, (const unsigned*)xr,
                                                 startA, cnt, colA, att1, bias1, h);
    k_bnstats<<<512, 256, 0, stream>>>(h, bnsum + 0, bnsum + 128);
    k_bnfinal<<<1, 128, 0, stream>>>(bnsum + 0, bnsum + 128, g1, be1, scsh + 0, scsh + 128);

    // Layer 2 (BN1 apply + ReLU fused into GEMM A-staging)
    k_gemm<true><<<gemm_grid, 256, 0, stream>>>(h, Wl2, bl2, Wr2, br2,
                                                scsh + 0, scsh + 128, xl, xr, N_NODES);
    k_agg<<<(N_NODES + 3) / 4, 256, 0, stream>>>((const unsigned*)xl, (const unsigned*)xr,
                                                 startA, cnt, colA, att2, bias2, h);
    k_bnstats<<<512, 256, 0, stream>>>(h, bnsum + 256, bnsum + 384);
    k_bnfinal<<<1, 128, 0, stream>>>(bnsum + 256, bnsum + 384, g2, be2, scsh + 256, scsh + 384);

    // Pool (BN2 apply + ReLU fused) + MLP
    k_pool<<<(NG + 3) / 4, 256, 0, stream>>>(h, gstart, gf, scsh + 256, scsh + 384, z);
    k_mlp<<<NG, 256, 0, stream>>>(z, Wfc1, bfc1, Wfc2, bfc2, out);
}

// Round 4
// 481.185 us; speedup vs baseline: 2.3086x; 1.3698x over previous
//
#include <hip/hip_runtime.h>

#define N_NODES 100000
#define E_EDGES 1600000
#define EP (E_EDGES + N_NODES)
#define NG 1024
#define NEG 0.2f
#define EPS_BN 1e-5f

#define NB 196        // dst buckets of 512 nodes
#define BCAP 12288    // per-bucket capacity (mean 8704, +38 sigma)

typedef __attribute__((ext_vector_type(8))) short bf8_t;
typedef __attribute__((ext_vector_type(4))) float f4_t;

__device__ __forceinline__ unsigned short f2b(float f) {   // f32 -> bf16 RNE
    unsigned u = __float_as_uint(f);
    u += 0x7FFF + ((u >> 16) & 1);
    return (unsigned short)(u >> 16);
}

// ================= CSR build: partition -> histogram -> scan -> place =======
__global__ __launch_bounds__(256) void k_part(const int* __restrict__ ei,
                                              int* __restrict__ bucketCur,
                                              int2* __restrict__ buf) {
    __shared__ int lh[NB], lb[NB];
    int t = threadIdx.x;
    for (int i = t; i < NB; i += 256) lh[i] = 0;
    __syncthreads();
    int base = blockIdx.x * 4096;
    int2 e[16];
    int rk[16];
#pragma unroll
    for (int i = 0; i < 16; i++) {
        int idx = base + i * 256 + t;
        int s, d;
        if (idx < E_EDGES) { s = ei[idx]; d = ei[E_EDGES + idx]; }
        else if (idx < EP) { s = d = idx - E_EDGES; }
        else { s = -1; d = -1; }
        e[i].x = s; e[i].y = d;
        rk[i] = (d >= 0) ? atomicAdd(&lh[d >> 9], 1) : 0;
    }
    __syncthreads();
    for (int i = t; i < NB; i += 256) lb[i] = atomicAdd(&bucketCur[i], lh[i]);
    __syncthreads();
#pragma unroll
    for (int i = 0; i < 16; i++) {
        int d = e[i].y;
        if (d >= 0) {
            int bkt = d >> 9;
            buf[(size_t)bkt * BCAP + lb[bkt] + rk[i]] = e[i];
        }
    }
}

__global__ __launch_bounds__(256) void k_build_a(const int2* __restrict__ buf,
                                                 const int* __restrict__ bcnt,
                                                 int* __restrict__ cnt) {
    __shared__ int h[512];
    int b = blockIdx.x, t = threadIdx.x;
    for (int i = t; i < 512; i += 256) h[i] = 0;
    __syncthreads();
    int n = bcnt[b];
    const int2* p = buf + (size_t)b * BCAP;
    for (int i = t; i < n; i += 256) atomicAdd(&h[p[i].y & 511], 1);
    __syncthreads();
    int base = b << 9;
    for (int i = t; i < 512; i += 256) {
        int d = base + i;
        if (d < N_NODES) cnt[d] = h[i];
    }
}

__global__ __launch_bounds__(256) void k_s1(const int* __restrict__ cnt,
                                            int* __restrict__ bsum) {
    int b = blockIdx.x, t = threadIdx.x;
    int idx = b * 256 + t;
    int v = (idx < N_NODES) ? cnt[idx] : 0;
#pragma unroll
    for (int o = 1; o < 64; o <<= 1) v += __shfl_xor(v, o, 64);
    __shared__ int ws[4];
    if ((t & 63) == 0) ws[t >> 6] = v;
    __syncthreads();
    if (t == 0) bsum[b] = ws[0] + ws[1] + ws[2] + ws[3];
}

__global__ __launch_bounds__(512) void k_s2(const int* __restrict__ bsum,
                                            int* __restrict__ bbase,
                                            int* __restrict__ startA) {
    __shared__ int s[512];
    int t = threadIdx.x;
    int v = (t < 391) ? bsum[t] : 0;
    s[t] = v;
    __syncthreads();
    for (int o = 1; o < 512; o <<= 1) {
        int u = (t >= o) ? s[t - o] : 0;
        __syncthreads();
        s[t] += u;
        __syncthreads();
    }
    if (t < 391) bbase[t] = s[t] - v;   // exclusive
    if (t == 0) startA[N_NODES] = EP;
}

__global__ __launch_bounds__(256) void k_s3(const int* __restrict__ cnt,
                                            const int* __restrict__ bbase,
                                            int* __restrict__ startA) {
    __shared__ int s[256];
    int b = blockIdx.x, t = threadIdx.x;
    int idx = b * 256 + t;
    int v = (idx < N_NODES) ? cnt[idx] : 0;
    s[t] = v;
    __syncthreads();
    for (int o = 1; o < 256; o <<= 1) {
        int u = (t >= o) ? s[t - o] : 0;
        __syncthreads();
        s[t] += u;
        __syncthreads();
    }
    if (idx < N_NODES) startA[idx] = bbase[b] + s[t] - v;
}

__global__ __launch_bounds__(256) void k_build_b(const int2* __restrict__ buf,
                                                 const int* __restrict__ bcnt,
                                                 const int* __restrict__ startA,
                                                 int* __restrict__ colA) {
    __shared__ int h[512];
    int b = blockIdx.x, t = threadIdx.x;
    for (int i = t; i < 512; i += 256) h[i] = 0;
    __syncthreads();
    int n = bcnt[b];
    const int2* p = buf + (size_t)b * BCAP;
    for (int i = t; i < n; i += 256) {
        int2 e = p[i];
        int r = atomicAdd(&h[e.y & 511], 1);
        colA[startA[e.y] + r] = e.x;
    }
}

// ================= W preconvert: f32 [k][n] -> bf16 swizzled LDS image ======
__global__ void k_wconv(const float* __restrict__ Wl, const float* __restrict__ Wr,
                        unsigned short* __restrict__ img) {
    int g = blockIdx.x * 256 + threadIdx.x;   // 4096 chunks
    int m = g >> 11, n = (g >> 4) & 127, kb = g & 15;
    const float* W = m ? Wr : Wl;
    unsigned short v[8];
#pragma unroll
    for (int j = 0; j < 8; j++) v[j] = f2b(W[(kb * 8 + j) * 128 + n]);
    int off = ((n * 256 + kb * 16) ^ ((n & 7) << 4)) + m * 32768;
    *(int4*)((char*)img + off) = *(int4*)v;
}

// ================= MFMA dual GEMM: xl = A@Wl + bl, xr = A@Wr + br (bf16) =====
template<bool AFF>
__global__ __launch_bounds__(256) void k_gemm(
    const float* __restrict__ A, const unsigned short* __restrict__ Wimg,
    const float* __restrict__ bl, const float* __restrict__ br,
    const float* __restrict__ sc, const float* __restrict__ sh,
    unsigned short* __restrict__ xl, unsigned short* __restrict__ xr, int M)
{
    __shared__ char lds[81920];
    short* As = (short*)lds;             // 16384 B
    short* Wt = (short*)(lds + 16384);   // 65536 B

    int t = threadIdx.x;
    int lane = t & 63;
    int w = t >> 6;
    int brow = blockIdx.x * 64;

    // ---- stage W: linear 64KB copy (image pre-swizzled by k_wconv) ----
    {
        const int4* src = (const int4*)Wimg;
        int4* dst = (int4*)Wt;
#pragma unroll
        for (int r = 0; r < 16; ++r) dst[r * 256 + t] = src[r * 256 + t];
    }

    // ---- stage A (convert + optional BN-affine + relu) ----
    {
        int kbase = (t & 7) * 16;
        float scv[16], shv[16];
        if (AFF) {
#pragma unroll
            for (int q = 0; q < 4; ++q) {
                float4 a4 = *(const float4*)&sc[kbase + q * 4];
                float4 b4 = *(const float4*)&sh[kbase + q * 4];
                scv[q*4+0]=a4.x; scv[q*4+1]=a4.y; scv[q*4+2]=a4.z; scv[q*4+3]=a4.w;
                shv[q*4+0]=b4.x; shv[q*4+1]=b4.y; shv[q*4+2]=b4.z; shv[q*4+3]=b4.w;
            }
        }
#pragma unroll
        for (int p = 0; p < 2; ++p) {
            int row = p * 32 + (t >> 3);
            int ar = brow + row; if (ar >= M) ar = M - 1;
            const float* src = &A[(size_t)ar * 128 + kbase];
            unsigned short vb[16];
#pragma unroll
            for (int q = 0; q < 4; ++q) {
                float4 x4 = *(const float4*)&src[q * 4];
                float vv[4] = {x4.x, x4.y, x4.z, x4.w};
#pragma unroll
                for (int e = 0; e < 4; ++e) {
                    float f = vv[e];
                    if (AFF) f = fmaxf(fmaf(f, scv[q*4+e], shv[q*4+e]), 0.f);
                    vb[q * 4 + e] = f2b(f);
                }
            }
            int swz = (row & 7) << 4;
#pragma unroll
            for (int u = 0; u < 2; ++u) {
                int off = (row * 256 + kbase * 2 + u * 16) ^ swz;
                *(int4*)((char*)As + off) = *(int4*)&vb[u * 8];
            }
        }
    }
    __syncthreads();

    // ---- compute ----
    int rl = lane & 15;
    int kh = lane >> 4;
    int mat = w >> 1;
    int c0 = (w & 1) * 64;
    int swz = (rl & 7) << 4;

    f4_t acc[4][4];
#pragma unroll
    for (int i = 0; i < 4; ++i)
#pragma unroll
        for (int j = 0; j < 4; ++j) { f4_t z = {0.f,0.f,0.f,0.f}; acc[i][j] = z; }

    const char* Asc = (const char*)As;
    const char* Wtc = (const char*)Wt + mat * 32768;

#pragma unroll
    for (int s = 0; s < 4; ++s) {
        int kb2 = (s * 32 + kh * 8) * 2;
        bf8_t af[4], bfr[4];
#pragma unroll
        for (int i = 0; i < 4; ++i) {
            int row = 16 * i + rl;
            af[i] = *(const bf8_t*)(Asc + ((row * 256 + kb2) ^ swz));
        }
#pragma unroll
        for (int j = 0; j < 4; ++j) {
            int n = c0 + 16 * j + rl;
            bfr[j] = *(const bf8_t*)(Wtc + ((n * 256 + kb2) ^ swz));
        }
#pragma unroll
        for (int i = 0; i < 4; ++i)
#pragma unroll
            for (int j = 0; j < 4; ++j)
                acc[i][j] = __builtin_amdgcn_mfma_f32_16x16x32_bf16(af[i], bfr[j], acc[i][j], 0, 0, 0);
    }

    // ---- epilogue: bias + bf16, bounce through LDS for coalesced stores ----
    __syncthreads();
    short* Cs = (short*)lds;   // [64][256] bf16, swizzled
    const float* bb = mat ? br : bl;
    float blv[4];
#pragma unroll
    for (int j = 0; j < 4; ++j) blv[j] = bb[c0 + 16 * j + rl];
    int colbase = mat * 128 + c0;
#pragma unroll
    for (int i = 0; i < 4; ++i)
#pragma unroll
        for (int j = 0; j < 4; ++j) {
            int col = colbase + 16 * j + rl;
#pragma unroll
            for (int q = 0; q < 4; ++q) {
                int row = 16 * i + kh * 4 + q;
                int off = (row * 512 + col * 2) ^ ((row & 7) << 4);
                *(short*)((char*)Cs + off) = (short)f2b(acc[i][j][q] + blv[j]);
            }
        }
    __syncthreads();
#pragma unroll
    for (int rep = 0; rep < 8; ++rep) {
        int unit = rep * 256 + t;
        int row = unit >> 5;
        int slot = unit & 31;
        int gr = brow + row;
        if (gr < M) {
            int off = (row * 512 + slot * 16) ^ ((row & 7) << 4);
            int4 vv = *(const int4*)((char*)Cs + off);
            unsigned short* O = (slot < 16) ? xl : xr;
            int gcol = (slot & 15) * 8;
            *(int4*)&O[(size_t)gr * 128 + gcol] = vv;
        }
    }
}

// ================= fused edge softmax + aggregation (depth-4 pipeline) ======
__global__ __launch_bounds__(256) void k_agg(
    const unsigned* __restrict__ xl, const unsigned* __restrict__ xr,
    const int* __restrict__ startA, const int* __restrict__ colA,
    const float* __restrict__ att, const float* __restrict__ bias,
    float* __restrict__ out) {
    int wave = threadIdx.x >> 6;
    int lane = threadIdx.x & 63;
    int n = blockIdx.x * 4 + wave;
    if (n >= N_NODES) return;
    int c0 = lane * 2;

    float att0 = att[c0], att1 = att[c0 + 1];
    unsigned uxr = xr[(size_t)n * 64 + lane];
    float xr0 = __uint_as_float(uxr << 16);
    float xr1 = __uint_as_float(uxr & 0xFFFF0000u);
    int s0 = startA[n];
    int cn = startA[n + 1] - s0;   // >= 1 (self loop)

    float acc0 = 0.f, acc1 = 0.f, wsum = 0.f;

    int myS = (lane < cn) ? colA[s0 + lane] : 0;
#define LDROW(J) xl[(size_t)__shfl(myS, (J) & 63, 64) * 64 + lane]
    unsigned u0 = LDROW(0);
    unsigned u1 = (cn > 1) ? LDROW(1) : u0;
    unsigned u2 = (cn > 2) ? LDROW(2) : u0;
    unsigned u3 = (cn > 3) ? LDROW(3) : u0;

    for (int j = 0; j < cn; ++j) {
        unsigned un = u3;
        int jn = j + 4;
        if (jn < cn) {
            if ((jn & 63) == 0)
                myS = (jn + lane < cn) ? colA[s0 + jn + lane] : 0;
            un = LDROW(jn);
        }
        float v0 = __uint_as_float(u0 << 16);
        float v1 = __uint_as_float(u0 & 0xFFFF0000u);
        float e0 = v0 + xr0; e0 = (e0 > 0.f) ? e0 : NEG * e0;
        float e1 = v1 + xr1; e1 = (e1 > 0.f) ? e1 : NEG * e1;
        float p = e0 * att0 + e1 * att1;
        p += __shfl_xor(p, 1, 64);
        p += __shfl_xor(p, 2, 64);
        p += __shfl_xor(p, 4, 64);
        p += __shfl_xor(p, 8, 64);
        float wg = __expf(p);
        acc0 = fmaf(wg, v0, acc0);
        acc1 = fmaf(wg, v1, acc1);
        wsum += wg;
        u0 = u1; u1 = u2; u2 = u3; u3 = un;
    }
#undef LDROW
    float inv = 1.f / wsum;
    float2 o;
    o.x = acc0 * inv + bias[c0];
    o.y = acc1 * inv + bias[c0 + 1];
    *(float2*)&out[(size_t)n * 128 + c0] = o;
}

// ================= BatchNorm stats + finalize ================================
__global__ __launch_bounds__(256) void k_bnstats(const float* __restrict__ h,
                                                 float* __restrict__ gsum,
                                                 float* __restrict__ gsq) {
    int t = threadIdx.x;
    int c = t & 127;
    int half = t >> 7;
    float s = 0.f, q = 0.f;
    for (int r = blockIdx.x * 2 + half; r < N_NODES; r += gridDim.x * 2) {
        float v = h[(size_t)r * 128 + c];
        s += v;
        q = fmaf(v, v, q);
    }
    __shared__ float ls[256], lq[256];
    ls[t] = s; lq[t] = q;
    __syncthreads();
    if (t < 128) {
        atomicAdd(&gsum[c], ls[t] + ls[t + 128]);
        atomicAdd(&gsq[c],  lq[t] + lq[t + 128]);
    }
}

__global__ void k_bnfinal(const float* __restrict__ gsum, const float* __restrict__ gsq,
                          const float* __restrict__ g, const float* __restrict__ be,
                          float* __restrict__ sc, float* __restrict__ sh) {
    int c = threadIdx.x;   // 128
    float mu = gsum[c] * (1.f / N_NODES);
    float var = gsq[c] * (1.f / N_NODES) - mu * mu;
    float s = rsqrtf(var + EPS_BN) * g[c];
    sc[c] = s;
    sh[c] = be[c] - mu * s;
}

// ================= graph boundaries (batch is sorted) ========================
__global__ void k_gstart(const int* __restrict__ batch, int* __restrict__ gstart) {
    int i = blockIdx.x * 256 + threadIdx.x;
    if (i >= N_NODES) return;
    int b = batch[i];
    int prev = (i == 0) ? -1 : batch[i - 1];
    for (int g = prev + 1; g <= b; g++) gstart[g] = i;
    if (i == N_NODES - 1)
        for (int g = b + 1; g <= NG; g++) gstart[g] = N_NODES;
}

// ================= mean pool (fused BN2 affine+relu) + concat ================
__global__ __launch_bounds__(256) void k_pool(const float* __restrict__ h,
                                              const int* __restrict__ gstart,
                                              const float* __restrict__ gf,
                                              const float* __restrict__ sc,
                                              const float* __restrict__ sh,
                                              float* __restrict__ z) {
    int wave = threadIdx.x >> 6;
    int lane = threadIdx.x & 63;
    int g = blockIdx.x * 4 + wave;
    if (g >= NG) return;
    int c0 = lane * 2;
    float sc0 = sc[c0], sc1 = sc[c0 + 1], sh0 = sh[c0], sh1 = sh[c0 + 1];
    int r0 = gstart[g], r1 = gstart[g + 1];
    float s0 = 0.f, s1 = 0.f;
    for (int r = r0; r < r1; r++) {
        float2 v = *(const float2*)&h[(size_t)r * 128 + c0];
        s0 += fmaxf(fmaf(v.x, sc0, sh0), 0.f);
        s1 += fmaxf(fmaf(v.y, sc1, sh1), 0.f);
    }
    float invc = 1.f / fmaxf((float)(r1 - r0), 1.f);
    float2 o; o.x = s0 * invc; o.y = s1 * invc;
    *(float2*)&z[(size_t)g * 160 + c0] = o;
    if (lane < 16) {
        float2 gv = *(const float2*)&gf[(size_t)g * 32 + lane * 2];
        *(float2*)&z[(size_t)g * 160 + 128 + lane * 2] = gv;
    }
}

// ================= MLP head ==================================================
__global__ __launch_bounds__(256) void k_mlp(const float* __restrict__ z,
                                             const float* __restrict__ W1,
                                             const float* __restrict__ b1,
                                             const float* __restrict__ W2,
                                             const float* __restrict__ b2,
                                             float* __restrict__ out) {
    __shared__ float zs[160];
    __shared__ float red[4];
    int g = blockIdx.x;
    int t = threadIdx.x;
    if (t < 160) zs[t] = z[(size_t)g * 160 + t];
    __syncthreads();
    float acc = b1[t];
#pragma unroll 8
    for (int i = 0; i < 160; i++) acc = fmaf(zs[i], W1[i * 256 + t], acc);
    acc = fmaxf(acc, 0.f);
    float part = acc * W2[t];
    part += __shfl_xor(part, 32, 64);
    part += __shfl_xor(part, 16, 64);
    part += __shfl_xor(part, 8, 64);
    part += __shfl_xor(part, 4, 64);
    part += __shfl_xor(part, 2, 64);
    part += __shfl_xor(part, 1, 64);
    if ((t & 63) == 0) red[t >> 6] = part;
    __syncthreads();
    if (t == 0) out[g] = red[0] + red[1] + red[2] + red[3] + b2[0];
}

extern "C" void kernel_launch(void* const* d_in, const int* in_sizes, int n_in,
                              void* d_out, int out_size, void* d_ws, size_t ws_size,
                              hipStream_t stream) {
    (void)in_sizes; (void)n_in; (void)out_size; (void)ws_size;

    const float* x     = (const float*)d_in[0];
    const int*   ei    = (const int*)d_in[1];
    const int*   batch = (const int*)d_in[2];
    const float* gf    = (const float*)d_in[3];
    const float* Wl1 = (const float*)d_in[4];
    const float* bl1 = (const float*)d_in[5];
    const float* Wr1 = (const float*)d_in[6];
    const float* br1 = (const float*)d_in[7];
    const float* att1  = (const float*)d_in[8];
    const float* bias1 = (const float*)d_in[9];
    const float* g1  = (const float*)d_in[10];
    const float* be1 = (const float*)d_in[11];
    const float* Wl2 = (const float*)d_in[12];
    const float* bl2 = (const float*)d_in[13];
    const float* Wr2 = (const float*)d_in[14];
    const float* br2 = (const float*)d_in[15];
    const float* att2  = (const float*)d_in[16];
    const float* bias2 = (const float*)d_in[17];
    const float* g2  = (const float*)d_in[18];
    const float* be2 = (const float*)d_in[19];
    const float* Wfc1 = (const float*)d_in[20];
    const float* bfc1 = (const float*)d_in[21];
    const float* Wfc2 = (const float*)d_in[22];
    const float* bfc2 = (const float*)d_in[23];
    float* out = (float*)d_out;

    char* ws = (char*)d_ws;
    unsigned short* xl = (unsigned short*)(ws + 0);            // 25.6 MB bf16
    unsigned short* xr = (unsigned short*)(ws + 25600000);     // 25.6 MB bf16
    float* h        = (float*)(ws + 51200000);                 // 51.2 MB f32
    int*   colA     = (int*)(ws + 102400000);                  // 6.8 MB
    int2*  bktBuf   = (int2*)(ws + 109200000);                 // 19.27 MB
    int*   bucketCur= (int*)(ws + 128467584);                  // 1 KB   } zeroed
    float* bnsum    = (float*)(ws + 128468608);                // 2 KB   } together
    int*   cnt      = (int*)(ws + 128470656);                  // 400 KB
    int*   startA   = (int*)(ws + 128871040);                  // 400 KB (100001)
    int*   bsum     = (int*)(ws + 129271168);
    int*   bbase    = (int*)(ws + 129272960);
    float* scsh     = (float*)(ws + 129274752);                // sc1|sh1|sc2|sh2
    int*   gstart   = (int*)(ws + 129276800);
    float* z        = (float*)(ws + 129281152);
    unsigned short* Wimg = (unsigned short*)(ws + 129936512);  // 64 KB

    // zero: bucketCur (1024) + bnsum (2048) — contiguous
    hipMemsetAsync(bucketCur, 0, 1024 + 2048, stream);

    // CSR build (shared by both layers) + graph boundaries
    k_part<<<(EP + 4095) / 4096, 256, 0, stream>>>(ei, bucketCur, bktBuf);
    k_gstart<<<(N_NODES + 255) / 256, 256, 0, stream>>>(batch, gstart);
    k_build_a<<<NB, 256, 0, stream>>>(bktBuf, bucketCur, cnt);
    k_s1<<<391, 256, 0, stream>>>(cnt, bsum);
    k_s2<<<1, 512, 0, stream>>>(bsum, bbase, startA);
    k_s3<<<391, 256, 0, stream>>>(cnt, bbase, startA);
    k_build_b<<<NB, 256, 0, stream>>>(bktBuf, bucketCur, startA, colA);

    int gemm_grid = (N_NODES + 63) / 64;

    // Layer 1
    k_wconv<<<16, 256, 0, stream>>>(Wl1, Wr1, Wimg);
    k_gemm<false><<<gemm_grid, 256, 0, stream>>>(x, Wimg, bl1, br1,
                                                 nullptr, nullptr, xl, xr, N_NODES);
    k_agg<<<(N_NODES + 3) / 4, 256, 0, stream>>>((const unsigned*)xl, (const unsigned*)xr,
                                                 startA, colA, att1, bias1, h);
    k_bnstats<<<512, 256, 0, stream>>>(h, bnsum + 0, bnsum + 128);
    k_bnfinal<<<1, 128, 0, stream>>>(bnsum + 0, bnsum + 128, g1, be1, scsh + 0, scsh + 128);

    // Layer 2 (BN1 apply + ReLU fused into GEMM A-staging)
    k_wconv<<<16, 256, 0, stream>>>(Wl2, Wr2, Wimg);
    k_gemm<true><<<gemm_grid, 256, 0, stream>>>(h, Wimg, bl2, br2,
                                                scsh + 0, scsh + 128, xl, xr, N_NODES);
    k_agg<<<(N_NODES + 3) / 4, 256, 0, stream>>>((const unsigned*)xl, (const unsigned*)xr,
                                                 startA, colA, att2, bias2, h);
    k_bnstats<<<512, 256, 0, stream>>>(h, bnsum + 256, bnsum + 384);
    k_bnfinal<<<1, 128, 0, stream>>>(bnsum + 256, bnsum + 384, g2, be2, scsh + 256, scsh + 384);

    // Pool (BN2 apply + ReLU fused) + MLP
    k_pool<<<(NG + 3) / 4, 256, 0, stream>>>(h, gstart, gf, scsh + 256, scsh + 384, z);
    k_mlp<<<NG, 256, 0, stream>>>(z, Wfc1, bfc1, Wfc2, bfc2, out);
}